// Round 12
// baseline (4100665.234 us; speedup 1.0000x reference)
//
#include <hip/hip_runtime.h>
#include <hip/hip_bf16.h>
#include <cstdint>

#define B_  32
#define T_  1000
#define F_  161
#define H_  512
#define C_  62
#define BT_ 32000
#define TC  200          // time-chunk length
#define NCH 5            // number of chunks
#define MCH (B_ * TC)    // rows per chunk gemm = 6400
#define ESC_TRIES (1 << 14)   // bounded poll escape (diagnostic, never hit normally)

typedef __bf16 bf16x8 __attribute__((ext_vector_type(8)));
typedef float  f32x4  __attribute__((ext_vector_type(4)));
typedef unsigned short us8 __attribute__((ext_vector_type(8)));

__device__ __forceinline__ float b2f(unsigned short s) {
    union { unsigned int i; float f; } v; v.i = (unsigned int)s << 16; return v.f;
}
__device__ __forceinline__ unsigned short f2b(float f) {
    unsigned int u = __float_as_uint(f);
    unsigned int r = u + 0x7fffu + ((u >> 16) & 1u);   // RNE
    return (unsigned short)(r >> 16);
}

// Proven XCD-local rendezvous pair (R11): sc0 store -> L2, sc0 load bypasses stale L1.
__device__ __forceinline__ unsigned int ld_sc0_u32(const unsigned int* p) {
    unsigned int v;
    asm volatile("global_load_dword %0, %1, off sc0\n\ts_waitcnt vmcnt(0)"
                 : "=&v"(v) : "v"(p) : "memory");
    return v;
}
__device__ __forceinline__ void st_sc0_u32(unsigned int* p, unsigned int v) {
    asm volatile("global_store_dword %0, %1, off sc0" :: "v"(p), "v"(v) : "memory");
}

// ---------------- conversion kernels ----------------

__global__ __launch_bounds__(256) void cvt_x_pad(const float* __restrict__ x,
                                                 unsigned short* __restrict__ xb) {
    int idx = blockIdx.x * 256 + threadIdx.x;
    if (idx >= BT_ * 192) return;
    int r = idx / 192, k = idx - r * 192;
    float v = (k < F_) ? x[(size_t)r * F_ + k] : 0.f;
    xb[idx] = f2b(v);
}

// dst[n*KP + k] = bf16(src[(k0+k)*N + n]) for k<K,n<N else 0.  dst is [NP][KP].
__global__ __launch_bounds__(256) void transpose_cvt(const float* __restrict__ src,
                                                     unsigned short* __restrict__ dst,
                                                     int K, int N, int k0, int KP, int NP) {
    int idx = blockIdx.x * 256 + threadIdx.x;
    if (idx >= NP * KP) return;
    int n = idx / KP, k = idx - n * KP;
    float v = (k < K && n < N) ? src[(size_t)(k0 + k) * N + n] : 0.f;
    dst[idx] = f2b(v);
}

// bcat[d*1536 + c] = (c<1024 ? bg_d[c] : bc_d[c-1024])
__global__ __launch_bounds__(256) void biascat(const float* __restrict__ bg_f,
                                               const float* __restrict__ bc_f,
                                               const float* __restrict__ bg_b,
                                               const float* __restrict__ bc_b,
                                               float* __restrict__ bcat) {
    int idx = blockIdx.x * 256 + threadIdx.x;
    if (idx >= 2 * 1536) return;
    int d = idx / 1536, c = idx - d * 1536;
    const float* bg = d ? bg_b : bg_f;
    const float* bc = d ? bc_b : bc_f;
    bcat[idx] = (c < 1024) ? bg[c] : bc[c - 1024];
}

// ---------------- GEMM ----------------

#define BM 128
#define BN 64
#define BK 64

template<bool RELU, int OMODE, bool AMAP>
__global__ __launch_bounds__(256) void gemm_bf16(const unsigned short* __restrict__ A,
                                                 const unsigned short* __restrict__ BT,
                                                 const float* __restrict__ bias,
                                                 void* __restrict__ Out,
                                                 int K, int Nreal, int t0) {
    __shared__ __align__(16) unsigned short As[BM * BK];
    __shared__ __align__(16) unsigned short Bs[BN * BK];
    const int tid  = threadIdx.x;
    const int lane = tid & 63;
    const int w    = tid >> 6;
    const int wm   = w & 1, wn = w >> 1;
    const int l15  = lane & 15, l4 = lane >> 4;
    const int m0   = blockIdx.x * BM;
    const int n0   = blockIdx.y * BN;

    const int ar = tid >> 1, ac = (tid & 1) * 32;
    const int br = tid >> 2, bc = (tid & 3) * 16;

    size_t arow;
    {
        int r = m0 + ar;
        if (AMAP) { int rb = r / TC; int rt = r - rb * TC; arow = (size_t)rb * T_ + t0 + rt; }
        else      arow = (size_t)r;
    }

    f32x4 acc[4][2] = {};

    for (int kt = 0; kt < K; kt += BK) {
        if (kt) __syncthreads();
        {
            const unsigned short* ga = A + arow * K + kt + ac;
            us8* la = (us8*)(As + ar * BK + ac);
            #pragma unroll
            for (int j = 0; j < 4; ++j) la[j] = *(const us8*)(ga + 8 * j);
            const unsigned short* gb = BT + (size_t)(n0 + br) * K + kt + bc;
            us8* lb = (us8*)(Bs + br * BK + bc);
            #pragma unroll
            for (int j = 0; j < 2; ++j) lb[j] = *(const us8*)(gb + 8 * j);
        }
        __syncthreads();
        #pragma unroll
        for (int kk = 0; kk < BK; kk += 32) {
            bf16x8 af[4], bfr[2];
            #pragma unroll
            for (int m = 0; m < 4; ++m)
                af[m] = *(const bf16x8*)(As + (wm * 64 + m * 16 + l15) * BK + kk + l4 * 8);
            #pragma unroll
            for (int n = 0; n < 2; ++n)
                bfr[n] = *(const bf16x8*)(Bs + (wn * 32 + n * 16 + l15) * BK + kk + l4 * 8);
            #pragma unroll
            for (int m = 0; m < 4; ++m)
                #pragma unroll
                for (int n = 0; n < 2; ++n)
                    acc[m][n] = __builtin_amdgcn_mfma_f32_16x16x32_bf16(af[m], bfr[n], acc[m][n], 0, 0, 0);
        }
    }

    const int rbase = m0 + wm * 64;
    const int cb    = n0 + wn * 32;
    #pragma unroll
    for (int m = 0; m < 4; ++m) {
        #pragma unroll
        for (int n = 0; n < 2; ++n) {
            int gc = cb + n * 16 + l15;
            if (gc < Nreal) {
                float bv = bias ? bias[gc] : 0.f;
                int gr0 = rbase + m * 16 + l4 * 4;
                #pragma unroll
                for (int r = 0; r < 4; ++r) {
                    float v = acc[m][n][r] + bv;
                    if (RELU) v = fmaxf(v, 0.f);
                    int gr = gr0 + r;
                    if (OMODE == 0) {
                        ((unsigned short*)Out)[(size_t)gr * Nreal + gc] = f2b(v);
                    } else {
                        int rb = gr / TC; int rt = gr - rb * TC;
                        size_t orow = (size_t)rb * T_ + t0 + rt;
                        ((float*)Out)[orow * Nreal + gc] += v;
                    }
                }
            }
        }
    }
}

// ---------------- persistent BiGRU chunk kernel (sc0 XCD-local exchange) ----------------
// Grid = 256 blocks (1/CU via 146 KB LDS -> co-resident; 32 per XCD). Blocks on XCD d (d<2)
// claim dir d roles (16 winners via atomicAdd); rest exit. All peers of a dir share one XCD.
// Exchange: sc0 stores + sc0 loads meet in that XCD's L2 (R11-proven; plain stores do NOT
// work — R10 hang). No agent atomics, no fences -> no fabric drains, X stays L2-cached.
// Barrier: per-dir flag array; __syncthreads drains sc0 data stores before the flag store.

__device__ __forceinline__ void stage_bcast(unsigned short* STG,
                                            const unsigned int* src, int tid) {
    const int bck = tid & 127;
    const int br0 = tid >> 7;
    const unsigned long long* s64 = (const unsigned long long*)src;
    const unsigned long long* a0 = s64 + (br0 +  0) * 128 + bck;
    const unsigned long long* a1 = s64 + (br0 +  4) * 128 + bck;
    const unsigned long long* a2 = s64 + (br0 +  8) * 128 + bck;
    const unsigned long long* a3 = s64 + (br0 + 12) * 128 + bck;
    const unsigned long long* a4 = s64 + (br0 + 16) * 128 + bck;
    const unsigned long long* a5 = s64 + (br0 + 20) * 128 + bck;
    const unsigned long long* a6 = s64 + (br0 + 24) * 128 + bck;
    const unsigned long long* a7 = s64 + (br0 + 28) * 128 + bck;
    unsigned long long v0, v1, v2, v3, v4, v5, v6, v7;
    asm volatile(
        "global_load_dwordx2 %0, %8, off sc0\n\t"
        "global_load_dwordx2 %1, %9, off sc0\n\t"
        "global_load_dwordx2 %2, %10, off sc0\n\t"
        "global_load_dwordx2 %3, %11, off sc0\n\t"
        "global_load_dwordx2 %4, %12, off sc0\n\t"
        "global_load_dwordx2 %5, %13, off sc0\n\t"
        "global_load_dwordx2 %6, %14, off sc0\n\t"
        "global_load_dwordx2 %7, %15, off sc0\n\t"
        "s_waitcnt vmcnt(0)"
        : "=&v"(v0), "=&v"(v1), "=&v"(v2), "=&v"(v3),
          "=&v"(v4), "=&v"(v5), "=&v"(v6), "=&v"(v7)
        : "v"(a0), "v"(a1), "v"(a2), "v"(a3),
          "v"(a4), "v"(a5), "v"(a6), "v"(a7)
        : "memory");
    const int swz = bck * 8;
    *(unsigned long long*)((char*)STG + (br0 +  0) * 1024 + (swz ^ (((br0 +  0) & 7) << 4))) = v0;
    *(unsigned long long*)((char*)STG + (br0 +  4) * 1024 + (swz ^ (((br0 +  4) & 7) << 4))) = v1;
    *(unsigned long long*)((char*)STG + (br0 +  8) * 1024 + (swz ^ (((br0 +  8) & 7) << 4))) = v2;
    *(unsigned long long*)((char*)STG + (br0 + 12) * 1024 + (swz ^ (((br0 + 12) & 7) << 4))) = v3;
    *(unsigned long long*)((char*)STG + (br0 + 16) * 1024 + (swz ^ (((br0 + 16) & 7) << 4))) = v4;
    *(unsigned long long*)((char*)STG + (br0 + 20) * 1024 + (swz ^ (((br0 + 20) & 7) << 4))) = v5;
    *(unsigned long long*)((char*)STG + (br0 + 24) * 1024 + (swz ^ (((br0 + 24) & 7) << 4))) = v6;
    *(unsigned long long*)((char*)STG + (br0 + 28) * 1024 + (swz ^ (((br0 + 28) & 7) << 4))) = v7;
}

__global__ __launch_bounds__(512) void gru_persist(const unsigned short* __restrict__ wh_f,
                                                   const unsigned short* __restrict__ wh_b,
                                                   const unsigned short* __restrict__ Xf,
                                                   const unsigned short* __restrict__ Xb,
                                                   const int* __restrict__ seq_lens,
                                                   float* __restrict__ hf32_glob,
                                                   unsigned int* __restrict__ hb_g,
                                                   unsigned int* __restrict__ rh_g,
                                                   unsigned int* __restrict__ flags,
                                                   int* __restrict__ claim,
                                                   unsigned short* __restrict__ of,
                                                   unsigned short* __restrict__ ob,
                                                   int t0f, int t0b, int base, int init) {
    __shared__ __align__(16) unsigned short WG[64 * 512];   // gate h-weights [col][k], swz
    __shared__ __align__(16) unsigned short WC[32 * 512];   // cand h-weights [col][k], swz
    __shared__ __align__(16) unsigned short STG[32 * 512];  // h (ph1) / rh (ph2), swz
    __shared__ __align__(16) unsigned short XGs[32 * 64];   // x-gate slice [b][64] (r|u)
    __shared__ __align__(16) unsigned short XCs[32 * 32];   // x-cand slice [b][32]
    __shared__ float USH[32][33];                           // u gate values [b][local col]
    __shared__ float HOWN[32][32];                          // own f32 h slice [b][local col]
    __shared__ int Ls[32];
    __shared__ int role_sh;

    const int tid = threadIdx.x;

    // ---- XCD-based role claim ----
    if (tid == 0) {
        unsigned int xcd;
        asm volatile("s_getreg_b32 %0, hwreg(HW_REG_XCC_ID)" : "=s"(xcd));
        xcd &= 7u;
        int r = -1;
        if (xcd < 2u) {
            int s = atomicAdd(&claim[xcd], 1);
            if (s < 16) r = (int)(xcd * 16u) + s;
        }
        role_sh = r;
    }
    __syncthreads();
    const int role = role_sh;
    if (role < 0) return;
    const int dir = role >> 4;
    const int g   = role & 15;

    const int lane = tid & 63;
    const int w   = tid >> 6;
    const int l15 = lane & 15, l4 = lane >> 4;

    const unsigned short* wh = dir ? wh_b : wh_f;
    const unsigned short* X  = dir ? Xb : Xf;
    unsigned short* out      = dir ? ob : of;
    const int t0 = dir ? t0b : t0f;
    float*        hf32 = hf32_glob + (size_t)dir * 32 * 512;
    unsigned int* hb   = hb_g + (size_t)dir * 32 * 256;   // [32 rows][256 u32] = 1024B/row
    unsigned int* rh   = rh_g + (size_t)dir * 32 * 256;
    unsigned int* flg  = flags + dir * 256;               // 16 flags x 16-u32 stride
    unsigned int* myflag = flg + g * 16;

    // ---- load recurrent weight slices into LDS (swizzle: byte ^= (col&7)<<4) ----
    for (int j = tid; j < 4096; j += 512) {
        int col = j >> 6, ck = j & 63;
        int srcc = (col < 32) ? (32 * g + col) : (512 + 32 * g + (col - 32));
        int dstb = col * 1024 + ((ck * 16) ^ ((col & 7) << 4));
        *(us8*)((char*)WG + dstb) = *(const us8*)(wh + (size_t)srcc * 512 + ck * 8);
    }
    for (int j = tid; j < 2048; j += 512) {
        int col = j >> 6, ck = j & 63;
        int dstb = col * 1024 + ((ck * 16) ^ ((col & 7) << 4));
        *(us8*)((char*)WC + dstb) = *(const us8*)(wh + (size_t)(1024 + 32 * g + col) * 512 + ck * 8);
    }
    if (tid < 32) {
        int L = seq_lens[tid];
        Ls[tid] = L < 0 ? 0 : (L > T_ ? T_ : L);
    }
    for (int j = tid; j < 1024; j += 512) {
        int row = j >> 5, lc = j & 31;
        HOWN[row][lc] = init ? 0.f : hf32[row * 512 + 32 * g + lc];
    }
    // stage XGs for step 0
    {
        int tt0 = dir ? (TC - 1) : 0;
        if (tid < 256) {
            int b = tid >> 3, part = tid & 7;
            int srcc = (part < 4) ? (32 * g + part * 8) : (512 + 32 * g + (part - 4) * 8);
            *(us8*)(XGs + b * 64 + part * 8) =
                *(const us8*)(X + ((size_t)b * TC + tt0) * 1536 + srcc);
        }
    }

    const int mt = w & 1, nt = w >> 1;           // phase1 tile (8 waves: 2x4)
    const int mt2 = w & 1, nt2 = (w >> 1) & 1;   // phase2 tile (waves 0-3: 2x2)

    for (int i = 0; i < TC; ++i) {
        const int tt = dir ? (TC - 1 - i) : i;
        const int t  = t0 + tt;

        // ---- phase-1 staging: h broadcast (sc0) + x-cand slice ----
        if (init && i == 0) {
            for (int j = tid; j < 4096; j += 512)
                *(unsigned long long*)((char*)STG + j * 8) = 0ull;
        } else {
            stage_bcast(STG, hb, tid);
        }
        if (tid < 128) {
            int b = tid >> 2, part = tid & 3;
            *(us8*)(XCs + b * 32 + part * 8) =
                *(const us8*)(X + ((size_t)b * TC + tt) * 1536 + 1024 + 32 * g + part * 8);
        }
        __syncthreads();

        // ---- gates MFMA: [32,512] @ [512,64]  (cols: 32 r | 32 u) ----
        f32x4 acc = {};
        {
            const int arow = mt * 16 + l15;
            const int bcol = nt * 16 + l15;
            const int sa = (arow & 7) << 4, sb2 = (bcol & 7) << 4;
            const char* pa = (const char*)STG + arow * 1024;
            const char* pb = (const char*)WG + bcol * 1024;
            #pragma unroll
            for (int kk = 0; kk < 16; ++kk) {
                int kb = kk * 64 + l4 * 16;
                bf16x8 a  = *(const bf16x8*)(pa + (kb ^ sa));
                bf16x8 bf = *(const bf16x8*)(pb + (kb ^ sb2));
                acc = __builtin_amdgcn_mfma_f32_16x16x32_bf16(a, bf, acc, 0, 0, 0);
            }
        }
        {
            const int colL = nt * 16 + l15;        // wave-uniform branch: nt<2 -> r, else u
            #pragma unroll
            for (int r = 0; r < 4; ++r) {
                int row = mt * 16 + l4 * 4 + r;
                float s = acc[r] + b2f(XGs[row * 64 + colL]);
                float sg = 1.f / (1.f + __expf(-s));
                if (colL < 32) {
                    int c = 32 * g + colL;
                    unsigned short ho = *(const unsigned short*)((const char*)STG + row * 1024 +
                                            ((c * 2) ^ ((row & 7) << 4)));
                    unsigned int pr = f2b(sg * b2f(ho));
                    unsigned int po = (unsigned int)__shfl_xor((int)pr, 1);
                    if (!(lane & 1))
                        st_sc0_u32(rh + row * 256 + 16 * g + (colL >> 1), pr | (po << 16));
                } else {
                    USH[row][colL - 32] = sg;
                }
            }
        }

        // ---- phase-1 barrier (sc0 flags; syncthreads drains data stores first) ----
        {
            unsigned int tgt = (unsigned)(base + 2 * i + 1);
            __syncthreads();
            if (tid == 0) st_sc0_u32(myflag, tgt);
            if (w == 0) {
                const unsigned int* fp = flg + lane * 16;
                int tries = 0;
                for (;;) {
                    unsigned int v = tgt;
                    if (lane < 16) v = ld_sc0_u32(fp);
                    if (__all(v >= tgt)) break;
                    if (++tries >= ESC_TRIES) break;   // diagnostic escape, never hit normally
                    __builtin_amdgcn_s_sleep(1);
                }
            }
            __syncthreads();
        }

        // ---- phase-2 staging: rh broadcast (sc0) ----
        stage_bcast(STG, rh, tid);
        __syncthreads();

        // ---- candidate MFMA (waves 0-3) + XGs prefetch for i+1 (waves 4-7) ----
        if (w < 4) {
            f32x4 acc2 = {};
            const int arow = mt2 * 16 + l15;
            const int bcol = nt2 * 16 + l15;
            const int sa = (arow & 7) << 4, sb2 = (bcol & 7) << 4;
            const char* pa = (const char*)STG + arow * 1024;
            const char* pb = (const char*)WC + bcol * 1024;
            #pragma unroll
            for (int kk = 0; kk < 16; ++kk) {
                int kb = kk * 64 + l4 * 16;
                bf16x8 a  = *(const bf16x8*)(pa + (kb ^ sa));
                bf16x8 bf = *(const bf16x8*)(pb + (kb ^ sb2));
                acc2 = __builtin_amdgcn_mfma_f32_16x16x32_bf16(a, bf, acc2, 0, 0, 0);
            }
            const int colL2 = nt2 * 16 + l15;
            const int col_c = 32 * g + colL2;
            #pragma unroll
            for (int r = 0; r < 4; ++r) {
                int row = mt2 * 16 + l4 * 4 + r;
                float s = acc2[r] + b2f(XCs[row * 32 + colL2]);
                float cv = tanhf(s);
                float uu = USH[row][colL2];
                float ho = HOWN[row][colL2];
                bool act = (t < Ls[row]);
                float hn = act ? (uu * ho + (1.f - uu) * cv) : ho;
                unsigned short hnb = f2b(hn);
                out[((size_t)row * TC + tt) * 512 + col_c] = act ? hnb : (unsigned short)0;
                unsigned int ph = hnb;
                unsigned int po = (unsigned int)__shfl_xor((int)ph, 1);
                if (!(lane & 1))
                    st_sc0_u32(hb + row * 256 + 16 * g + (colL2 >> 1), ph | (po << 16));
                HOWN[row][colL2] = hn;
            }
        } else if (i + 1 < TC) {
            int ttn = dir ? (tt - 1) : (tt + 1);
            int jd = tid - 256;
            int b = jd >> 3, part = jd & 7;
            int srcc = (part < 4) ? (32 * g + part * 8) : (512 + 32 * g + (part - 4) * 8);
            *(us8*)(XGs + b * 64 + part * 8) =
                *(const us8*)(X + ((size_t)b * TC + ttn) * 1536 + srcc);
        }

        // ---- phase-2 barrier ----
        {
            unsigned int tgt = (unsigned)(base + 2 * i + 2);
            __syncthreads();
            if (tid == 0) st_sc0_u32(myflag, tgt);
            if (w == 0) {
                const unsigned int* fp = flg + lane * 16;
                int tries = 0;
                for (;;) {
                    unsigned int v = tgt;
                    if (lane < 16) v = ld_sc0_u32(fp);
                    if (__all(v >= tgt)) break;
                    if (++tries >= ESC_TRIES) break;
                    __builtin_amdgcn_s_sleep(1);
                }
            }
            __syncthreads();
        }
    }

    // persist own f32 h slice for next chunk (plain stores; cross-launch coherence via
    // end-of-kernel release)
    for (int j = tid; j < 1024; j += 512) {
        int row = j >> 5, lc = j & 31;
        hf32[row * 512 + 32 * g + lc] = HOWN[row][lc];
    }
}

// ---------------- launcher ----------------

extern "C" void kernel_launch(void* const* d_in, const int* in_sizes, int n_in,
                              void* d_out, int out_size, void* d_ws, size_t ws_size,
                              hipStream_t stream) {
    (void)in_sizes; (void)n_in; (void)out_size; (void)ws_size;
    const float* x    = (const float*)d_in[0];
    const int*   seq  = (const int*)  d_in[1];
    const float* w1   = (const float*)d_in[2];
    const float* b1   = (const float*)d_in[3];
    const float* w2   = (const float*)d_in[4];
    const float* b2   = (const float*)d_in[5];
    const float* wg_f = (const float*)d_in[6];
    const float* bg_f = (const float*)d_in[7];
    const float* wc_f = (const float*)d_in[8];
    const float* bc_f = (const float*)d_in[9];
    const float* wg_b = (const float*)d_in[10];
    const float* bg_b = (const float*)d_in[11];
    const float* wc_b = (const float*)d_in[12];
    const float* bc_b = (const float*)d_in[13];
    const float* wf   = (const float*)d_in[14];
    const float* bfv  = (const float*)d_in[15];

    char* p = (char*)d_ws;
    auto alloc = [&](size_t bytes) { char* q = p; p += (bytes + 255) & ~(size_t)255; return q; };

    // persistent weight buffers
    unsigned short* w1T     = (unsigned short*)alloc(512 * 192 * 2);
    unsigned short* w2T     = (unsigned short*)alloc(512 * 512 * 2);
    unsigned short* wx_f    = (unsigned short*)alloc((size_t)1536 * 512 * 2);   // x-half (k0=0)
    unsigned short* wx_b    = (unsigned short*)alloc((size_t)1536 * 512 * 2);
    unsigned short* wh_f    = (unsigned short*)alloc((size_t)1536 * 512 * 2);   // h-half (k0=512)
    unsigned short* wh_b    = (unsigned short*)alloc((size_t)1536 * 512 * 2);
    unsigned short* wfT_top = (unsigned short*)alloc(64 * 512 * 2);
    unsigned short* wfT_bot = (unsigned short*)alloc(64 * 512 * 2);
    float*          bcat    = (float*)         alloc(2 * 1536 * 4);

    // hB persistent through chunk phase (32.8 MB)
    unsigned short* hB = (unsigned short*)alloc((size_t)BT_ * 512 * 2);

    // union region: {xb, h1} (front-end) aliases {Xf, Xb, of, ob} (chunk phase)
    char* U = alloc((size_t)MCH * 1536 * 2 * 2 + (size_t)MCH * 512 * 2 * 2);
    unsigned short* xb = (unsigned short*)U;
    unsigned short* h1 = (unsigned short*)(U + (size_t)BT_ * 192 * 2);
    unsigned short* Xf = (unsigned short*)U;
    unsigned short* Xb = (unsigned short*)(U + (size_t)MCH * 1536 * 2);
    unsigned short* of = (unsigned short*)(U + (size_t)MCH * 1536 * 2 * 2);
    unsigned short* ob = (unsigned short*)(U + (size_t)MCH * 1536 * 2 * 2 + (size_t)MCH * 512 * 2);

    // GRU state/comm (outside union). flags|claim contiguous for one memset.
    unsigned int*   flags    = (unsigned int*)alloc(2 * 256 * 4);   // 2048 B
    int*            claim    = (int*)         alloc(256);
    float*          hf32_gl  = (float*)       alloc((size_t)2 * 32 * 512 * 4);
    unsigned int*   hb_gl    = (unsigned int*)alloc((size_t)2 * 32 * 256 * 4);
    unsigned int*   rh_gl    = (unsigned int*)alloc((size_t)2 * 32 * 256 * 4);

    hipMemsetAsync(d_out, 0, (size_t)BT_ * C_ * 4, stream);
    hipMemsetAsync(flags, 0, 2 * 256 * 4 + 256, stream);

    // ---- weight prep ----
    transpose_cvt<<<(512 * 192) / 256, 256, 0, stream>>>(w1, w1T, 161, 512, 0, 192, 512);
    transpose_cvt<<<(512 * 512) / 256, 256, 0, stream>>>(w2, w2T, 512, 512, 0, 512, 512);
    transpose_cvt<<<(1024 * 512) / 256, 256, 0, stream>>>(wg_f, wx_f, 512, 1024, 0, 512, 1024);
    transpose_cvt<<<(512 * 512) / 256, 256, 0, stream>>>(wc_f, wx_f + (size_t)1024 * 512, 512, 512, 0, 512, 512);
    transpose_cvt<<<(1024 * 512) / 256, 256, 0, stream>>>(wg_b, wx_b, 512, 1024, 0, 512, 1024);
    transpose_cvt<<<(512 * 512) / 256, 256, 0, stream>>>(wc_b, wx_b + (size_t)1024 * 512, 512, 512, 0, 512, 512);
    transpose_cvt<<<(1024 * 512) / 256, 256, 0, stream>>>(wg_f, wh_f, 512, 1024, 512, 512, 1024);
    transpose_cvt<<<(512 * 512) / 256, 256, 0, stream>>>(wc_f, wh_f + (size_t)1024 * 512, 512, 512, 512, 512, 512);
    transpose_cvt<<<(1024 * 512) / 256, 256, 0, stream>>>(wg_b, wh_b, 512, 1024, 512, 512, 1024);
    transpose_cvt<<<(512 * 512) / 256, 256, 0, stream>>>(wc_b, wh_b + (size_t)1024 * 512, 512, 512, 512, 512, 512);
    transpose_cvt<<<(64 * 512) / 256, 256, 0, stream>>>(wf, wfT_top, 512, 62, 0, 512, 64);
    transpose_cvt<<<(64 * 512) / 256, 256, 0, stream>>>(wf, wfT_bot, 512, 62, 512, 512, 64);
    biascat<<<(2 * 1536 + 255) / 256, 256, 0, stream>>>(bg_f, bc_f, bg_b, bc_b, bcat);

    // ---- dense front-end ----
    cvt_x_pad<<<(BT_ * 192 + 255) / 256, 256, 0, stream>>>(x, xb);
    gemm_bf16<true, 0, false><<<dim3(BT_ / BM, 512 / BN), 256, 0, stream>>>(xb, w1T, b1, h1, 192, 512, 0);
    gemm_bf16<true, 0, false><<<dim3(BT_ / BM, 512 / BN), 256, 0, stream>>>(h1, w2T, b2, hB, 512, 512, 0);

    // ---- chunked BiGRU + projection ----
    for (int c = 0; c < NCH; ++c) {
        const int t0f = c * TC;
        const int t0b = (NCH - 1 - c) * TC;
        gemm_bf16<false, 0, true><<<dim3(MCH / BM, 1536 / BN), 256, 0, stream>>>(hB, wx_f, bcat,        Xf, 512, 1536, t0f);
        gemm_bf16<false, 0, true><<<dim3(MCH / BM, 1536 / BN), 256, 0, stream>>>(hB, wx_b, bcat + 1536, Xb, 512, 1536, t0b);
        gru_persist<<<256, 512, 0, stream>>>(wh_f, wh_b, Xf, Xb, seq, hf32_gl,
                                             hb_gl, rh_gl, flags, claim + 2 * c, of, ob,
                                             t0f, t0b, c * 2 * TC, c == 0 ? 1 : 0);
        gemm_bf16<false, 1, false><<<dim3(MCH / BM, 1), 256, 0, stream>>>(of, wfT_top, bfv,     d_out, 512, C_, t0f);
        gemm_bf16<false, 1, false><<<dim3(MCH / BM, 1), 256, 0, stream>>>(ob, wfT_bot, nullptr, d_out, 512, C_, t0b);
    }
}

// Round 13
// 7955.988 us; speedup vs baseline: 515.4188x; 515.4188x over previous
//
#include <hip/hip_runtime.h>
#include <hip/hip_bf16.h>
#include <cstdint>

#define B_  32
#define T_  1000
#define F_  161
#define H_  512
#define C_  62
#define BT_ 32000
#define TC  200          // time-chunk length
#define NCH 5            // number of chunks
#define MCH (B_ * TC)    // rows per chunk gemm = 6400
#define ESC_TRIES (1 << 14)   // bounded poll escape (diagnostic, never hit normally)

typedef __bf16 bf16x8 __attribute__((ext_vector_type(8)));
typedef float  f32x4  __attribute__((ext_vector_type(4)));
typedef unsigned short us8 __attribute__((ext_vector_type(8)));

__device__ __forceinline__ float b2f(unsigned short s) {
    union { unsigned int i; float f; } v; v.i = (unsigned int)s << 16; return v.f;
}
__device__ __forceinline__ unsigned short f2b(float f) {
    unsigned int u = __float_as_uint(f);
    unsigned int r = u + 0x7fffu + ((u >> 16) & 1u);   // RNE
    return (unsigned short)(r >> 16);
}

// ---------------- conversion kernels ----------------

__global__ __launch_bounds__(256) void cvt_x_pad(const float* __restrict__ x,
                                                 unsigned short* __restrict__ xb) {
    int idx = blockIdx.x * 256 + threadIdx.x;
    if (idx >= BT_ * 192) return;
    int r = idx / 192, k = idx - r * 192;
    float v = (k < F_) ? x[(size_t)r * F_ + k] : 0.f;
    xb[idx] = f2b(v);
}

// dst[n*KP + k] = bf16(src[(k0+k)*N + n]) for k<K,n<N else 0.  dst is [NP][KP].
__global__ __launch_bounds__(256) void transpose_cvt(const float* __restrict__ src,
                                                     unsigned short* __restrict__ dst,
                                                     int K, int N, int k0, int KP, int NP) {
    int idx = blockIdx.x * 256 + threadIdx.x;
    if (idx >= NP * KP) return;
    int n = idx / KP, k = idx - n * KP;
    float v = (k < K && n < N) ? src[(size_t)(k0 + k) * N + n] : 0.f;
    dst[idx] = f2b(v);
}

// bcat[d*1536 + c] = (c<1024 ? bg_d[c] : bc_d[c-1024])
__global__ __launch_bounds__(256) void biascat(const float* __restrict__ bg_f,
                                               const float* __restrict__ bc_f,
                                               const float* __restrict__ bg_b,
                                               const float* __restrict__ bc_b,
                                               float* __restrict__ bcat) {
    int idx = blockIdx.x * 256 + threadIdx.x;
    if (idx >= 2 * 1536) return;
    int d = idx / 1536, c = idx - d * 1536;
    const float* bg = d ? bg_b : bg_f;
    const float* bc = d ? bc_b : bc_f;
    bcat[idx] = (c < 1024) ? bg[c] : bc[c - 1024];
}

// ---------------- GEMM ----------------

#define BM 128
#define BN 64
#define BK 64

template<bool RELU, int OMODE, bool AMAP>
__global__ __launch_bounds__(256) void gemm_bf16(const unsigned short* __restrict__ A,
                                                 const unsigned short* __restrict__ BT,
                                                 const float* __restrict__ bias,
                                                 void* __restrict__ Out,
                                                 int K, int Nreal, int t0) {
    __shared__ __align__(16) unsigned short As[BM * BK];
    __shared__ __align__(16) unsigned short Bs[BN * BK];
    const int tid  = threadIdx.x;
    const int lane = tid & 63;
    const int w    = tid >> 6;
    const int wm   = w & 1, wn = w >> 1;
    const int l15  = lane & 15, l4 = lane >> 4;
    const int m0   = blockIdx.x * BM;
    const int n0   = blockIdx.y * BN;

    const int ar = tid >> 1, ac = (tid & 1) * 32;
    const int br = tid >> 2, bc = (tid & 3) * 16;

    size_t arow;
    {
        int r = m0 + ar;
        if (AMAP) { int rb = r / TC; int rt = r - rb * TC; arow = (size_t)rb * T_ + t0 + rt; }
        else      arow = (size_t)r;
    }

    f32x4 acc[4][2] = {};

    for (int kt = 0; kt < K; kt += BK) {
        if (kt) __syncthreads();
        {
            const unsigned short* ga = A + arow * K + kt + ac;
            us8* la = (us8*)(As + ar * BK + ac);
            #pragma unroll
            for (int j = 0; j < 4; ++j) la[j] = *(const us8*)(ga + 8 * j);
            const unsigned short* gb = BT + (size_t)(n0 + br) * K + kt + bc;
            us8* lb = (us8*)(Bs + br * BK + bc);
            #pragma unroll
            for (int j = 0; j < 2; ++j) lb[j] = *(const us8*)(gb + 8 * j);
        }
        __syncthreads();
        #pragma unroll
        for (int kk = 0; kk < BK; kk += 32) {
            bf16x8 af[4], bfr[2];
            #pragma unroll
            for (int m = 0; m < 4; ++m)
                af[m] = *(const bf16x8*)(As + (wm * 64 + m * 16 + l15) * BK + kk + l4 * 8);
            #pragma unroll
            for (int n = 0; n < 2; ++n)
                bfr[n] = *(const bf16x8*)(Bs + (wn * 32 + n * 16 + l15) * BK + kk + l4 * 8);
            #pragma unroll
            for (int m = 0; m < 4; ++m)
                #pragma unroll
                for (int n = 0; n < 2; ++n)
                    acc[m][n] = __builtin_amdgcn_mfma_f32_16x16x32_bf16(af[m], bfr[n], acc[m][n], 0, 0, 0);
        }
    }

    const int rbase = m0 + wm * 64;
    const int cb    = n0 + wn * 32;
    #pragma unroll
    for (int m = 0; m < 4; ++m) {
        #pragma unroll
        for (int n = 0; n < 2; ++n) {
            int gc = cb + n * 16 + l15;
            if (gc < Nreal) {
                float bv = bias ? bias[gc] : 0.f;
                int gr0 = rbase + m * 16 + l4 * 4;
                #pragma unroll
                for (int r = 0; r < 4; ++r) {
                    float v = acc[m][n][r] + bv;
                    if (RELU) v = fmaxf(v, 0.f);
                    int gr = gr0 + r;
                    if (OMODE == 0) {
                        ((unsigned short*)Out)[(size_t)gr * Nreal + gc] = f2b(v);
                    } else {
                        int rb = gr / TC; int rt = gr - rb * TC;
                        size_t orow = (size_t)rb * T_ + t0 + rt;
                        ((float*)Out)[orow * Nreal + gc] += v;
                    }
                }
            }
        }
    }
}

// ---------------- persistent BiGRU chunk kernel ----------------
// Transport (proven R9/R11, falsified alternatives R10/R12): relaxed AGENT atomics for ALL
// cross-block payloads+flags; placement = all 16 peers of a dir on ONE XCD (claim by
// HW_REG_XCC_ID) so agent ops resolve at the local L2 (FETCH stays low).
// Protocol: NO all-peer barriers. Per-peer epoch flags; wave w polls+stages peers {2w,2w+1}
// incrementally. Mailboxes double-buffered by step parity; WAR safety via the flag chain
// (publishing h(s+1) transitively proves consumption of slot s). __syncthreads' vmcnt drain
// orders data stores before the tid0 flag post; compiler fences pin poll->load order.

__device__ __forceinline__ void wait_flag(const unsigned int* f, unsigned int tgt) {
    int tries = 0;
    while (__hip_atomic_load(f, __ATOMIC_RELAXED, __HIP_MEMORY_SCOPE_AGENT) < tgt) {
        if (++tries >= ESC_TRIES) break;   // diagnostic escape, never hit normally
        __builtin_amdgcn_s_sleep(1);
    }
    asm volatile("" ::: "memory");         // no hoisting of data loads above the poll
}

// stage peer q's 2KB slice (32 rows x 16 u32) from mailbox into swizzled STG; one wave.
__device__ __forceinline__ void stage_peer(unsigned short* STG, const unsigned int* src,
                                           int q, int lane) {
    const unsigned long long* s64 = (const unsigned long long*)src;
    int row = lane >> 1, half = lane & 1;
    const unsigned long long* a = s64 + row * 128 + 8 * q + 4 * half;
    unsigned long long d0 = __hip_atomic_load(a + 0, __ATOMIC_RELAXED, __HIP_MEMORY_SCOPE_AGENT);
    unsigned long long d1 = __hip_atomic_load(a + 1, __ATOMIC_RELAXED, __HIP_MEMORY_SCOPE_AGENT);
    unsigned long long d2 = __hip_atomic_load(a + 2, __ATOMIC_RELAXED, __HIP_MEMORY_SCOPE_AGENT);
    unsigned long long d3 = __hip_atomic_load(a + 3, __ATOMIC_RELAXED, __HIP_MEMORY_SCOPE_AGENT);
    int bb  = 64 * q + 32 * half;
    int swz = (row & 7) << 4;
    char* rp = (char*)STG + row * 1024;
    *(unsigned long long*)(rp + ((bb +  0) ^ swz)) = d0;
    *(unsigned long long*)(rp + ((bb +  8) ^ swz)) = d1;
    *(unsigned long long*)(rp + ((bb + 16) ^ swz)) = d2;
    *(unsigned long long*)(rp + ((bb + 24) ^ swz)) = d3;
}

__global__ __launch_bounds__(512) void gru_persist(const unsigned short* __restrict__ wh_f,
                                                   const unsigned short* __restrict__ wh_b,
                                                   const unsigned short* __restrict__ Xf,
                                                   const unsigned short* __restrict__ Xb,
                                                   const int* __restrict__ seq_lens,
                                                   float* __restrict__ hf32_glob,
                                                   unsigned int* __restrict__ hb_g,
                                                   unsigned int* __restrict__ rh_g,
                                                   unsigned int* __restrict__ fH_g,
                                                   unsigned int* __restrict__ fR_g,
                                                   int* __restrict__ claim,
                                                   unsigned short* __restrict__ of,
                                                   unsigned short* __restrict__ ob,
                                                   int t0f, int t0b, int base, int init) {
    __shared__ __align__(16) unsigned short WG[64 * 512];   // gate h-weights [col][k], swz
    __shared__ __align__(16) unsigned short WC[32 * 512];   // cand h-weights [col][k], swz
    __shared__ __align__(16) unsigned short STG[32 * 512];  // h (ph1) / rh (ph2), swz
    __shared__ __align__(16) unsigned short XGs[32 * 64];   // x-gate slice [b][64] (r|u)
    __shared__ __align__(16) unsigned short XCs[32 * 32];   // x-cand slice [b][32]
    __shared__ float USH[32][33];                           // u gate values [b][local col]
    __shared__ float HOWN[32][32];                          // own f32 h slice [b][local col]
    __shared__ int Ls[32];
    __shared__ int role_sh;

    const int tid = threadIdx.x;

    // ---- XCD-based role claim (R11-proven: 1 block/CU -> 32 blocks per XCD) ----
    if (tid == 0) {
        unsigned int xcd;
        asm volatile("s_getreg_b32 %0, hwreg(HW_REG_XCC_ID)" : "=s"(xcd));
        xcd &= 7u;
        int r = -1;
        if (xcd < 2u) {
            int s = atomicAdd(&claim[xcd], 1);
            if (s < 16) r = (int)(xcd * 16u) + s;
        }
        role_sh = r;
    }
    __syncthreads();
    const int role = role_sh;
    if (role < 0) return;
    const int dir = role >> 4;
    const int g   = role & 15;

    const int lane = tid & 63;
    const int w   = tid >> 6;
    const int l15 = lane & 15, l4 = lane >> 4;

    const unsigned short* wh = dir ? wh_b : wh_f;
    const unsigned short* X  = dir ? Xb : Xf;
    unsigned short* out      = dir ? ob : of;
    const int t0 = dir ? t0b : t0f;
    float*        hf32 = hf32_glob + (size_t)dir * 32 * 512;
    // mailboxes: [dir][slot][32 rows][256 u32]
    unsigned int* hb0 = hb_g + (size_t)dir * 2 * 8192;
    unsigned int* rh0 = rh_g + (size_t)dir * 2 * 8192;
    unsigned int* fH  = fH_g + dir * 256;     // 16 peers x 16-u32 stride
    unsigned int* fR  = fR_g + dir * 256;
    unsigned int* myfH = fH + g * 16;
    unsigned int* myfR = fR + g * 16;

    // ---- load recurrent weight slices into LDS (swizzle: byte ^= (col&7)<<4) ----
    for (int j = tid; j < 4096; j += 512) {
        int col = j >> 6, ck = j & 63;
        int srcc = (col < 32) ? (32 * g + col) : (512 + 32 * g + (col - 32));
        int dstb = col * 1024 + ((ck * 16) ^ ((col & 7) << 4));
        *(us8*)((char*)WG + dstb) = *(const us8*)(wh + (size_t)srcc * 512 + ck * 8);
    }
    for (int j = tid; j < 2048; j += 512) {
        int col = j >> 6, ck = j & 63;
        int dstb = col * 1024 + ((ck * 16) ^ ((col & 7) << 4));
        *(us8*)((char*)WC + dstb) = *(const us8*)(wh + (size_t)(1024 + 32 * g + col) * 512 + ck * 8);
    }
    if (tid < 32) {
        int L = seq_lens[tid];
        Ls[tid] = L < 0 ? 0 : (L > T_ ? T_ : L);
    }
    for (int j = tid; j < 1024; j += 512) {
        int row = j >> 5, lc = j & 31;
        HOWN[row][lc] = init ? 0.f : hf32[row * 512 + 32 * g + lc];
    }
    // stage XGs for step 0
    {
        int tt0 = dir ? (TC - 1) : 0;
        if (tid < 256) {
            int b = tid >> 3, part = tid & 7;
            int srcc = (part < 4) ? (32 * g + part * 8) : (512 + 32 * g + (part - 4) * 8);
            *(us8*)(XGs + b * 64 + part * 8) =
                *(const us8*)(X + ((size_t)b * TC + tt0) * 1536 + srcc);
        }
    }

    const int mt = w & 1, nt = w >> 1;           // phase1 tile (8 waves: 2x4)
    const int mt2 = w & 1, nt2 = (w >> 1) & 1;   // phase2 tile (waves 0-3: 2x2)

    for (int i = 0; i < TC; ++i) {
        const int tt = dir ? (TC - 1 - i) : i;
        const int t  = t0 + tt;
        const unsigned int s = (unsigned)(base + i);     // absolute step epoch

        // ---- P1 staging: h(s-1) via per-peer poll+stage; XCs slice ----
        if (init && i == 0) {
            for (int j = tid; j < 4096; j += 512)
                *(unsigned long long*)((char*)STG + j * 8) = 0ull;
        } else {
            const unsigned int* hbs = hb0 + ((s - 1) & 1) * 8192;
            #pragma unroll
            for (int k = 0; k < 2; ++k) {
                int q = 2 * w + k;
                wait_flag(fH + q * 16, s);         // peer posted s after publishing h(s-1)
                stage_peer(STG, hbs, q, lane);
            }
        }
        if (tid < 128) {
            int b = tid >> 2, part = tid & 3;
            *(us8*)(XCs + b * 32 + part * 8) =
                *(const us8*)(X + ((size_t)b * TC + tt) * 1536 + 1024 + 32 * g + part * 8);
        }
        __syncthreads();

        // ---- gates MFMA: [32,512] @ [512,64]  (cols: 32 r | 32 u) ----
        f32x4 acc = {};
        {
            const int arow = mt * 16 + l15;
            const int bcol = nt * 16 + l15;
            const int sa = (arow & 7) << 4, sb2 = (bcol & 7) << 4;
            const char* pa = (const char*)STG + arow * 1024;
            const char* pb = (const char*)WG + bcol * 1024;
            #pragma unroll
            for (int kk = 0; kk < 16; ++kk) {
                int kb = kk * 64 + l4 * 16;
                bf16x8 a  = *(const bf16x8*)(pa + (kb ^ sa));
                bf16x8 bf = *(const bf16x8*)(pb + (kb ^ sb2));
                acc = __builtin_amdgcn_mfma_f32_16x16x32_bf16(a, bf, acc, 0, 0, 0);
            }
        }
        {
            unsigned int* rhs = rh0 + (s & 1) * 8192;
            const int colL = nt * 16 + l15;        // wave-uniform: nt<2 -> r, else u
            #pragma unroll
            for (int r = 0; r < 4; ++r) {
                int row = mt * 16 + l4 * 4 + r;
                float sv = acc[r] + b2f(XGs[row * 64 + colL]);
                float sg = 1.f / (1.f + __expf(-sv));
                if (colL < 32) {
                    int c = 32 * g + colL;
                    unsigned short ho = *(const unsigned short*)((const char*)STG + row * 1024 +
                                            ((c * 2) ^ ((row & 7) << 4)));
                    unsigned int pr = f2b(sg * b2f(ho));
                    unsigned int po = (unsigned int)__shfl_xor((int)pr, 1);
                    if (!(lane & 1))
                        __hip_atomic_store(rhs + row * 256 + 16 * g + (colL >> 1),
                                           pr | (po << 16),
                                           __ATOMIC_RELAXED, __HIP_MEMORY_SCOPE_AGENT);
                } else {
                    USH[row][colL - 32] = sg;
                }
            }
        }
        __syncthreads();                           // drains rh stores (vmcnt 0 per wave)
        if (tid == 0)
            __hip_atomic_store(myfR, s + 1, __ATOMIC_RELAXED, __HIP_MEMORY_SCOPE_AGENT);

        // ---- P2 staging: rh(s) via per-peer poll+stage ----
        {
            const unsigned int* rhs = rh0 + (s & 1) * 8192;
            #pragma unroll
            for (int k = 0; k < 2; ++k) {
                int q = 2 * w + k;
                wait_flag(fR + q * 16, s + 1);
                stage_peer(STG, rhs, q, lane);
            }
        }
        __syncthreads();

        // ---- candidate MFMA (waves 0-3) + XGs prefetch for i+1 (waves 4-7) ----
        if (w < 4) {
            f32x4 acc2 = {};
            const int arow = mt2 * 16 + l15;
            const int bcol = nt2 * 16 + l15;
            const int sa = (arow & 7) << 4, sb2 = (bcol & 7) << 4;
            const char* pa = (const char*)STG + arow * 1024;
            const char* pb = (const char*)WC + bcol * 1024;
            #pragma unroll
            for (int kk = 0; kk < 16; ++kk) {
                int kb = kk * 64 + l4 * 16;
                bf16x8 a  = *(const bf16x8*)(pa + (kb ^ sa));
                bf16x8 bf = *(const bf16x8*)(pb + (kb ^ sb2));
                acc2 = __builtin_amdgcn_mfma_f32_16x16x32_bf16(a, bf, acc2, 0, 0, 0);
            }
            unsigned int* hbs = hb0 + (s & 1) * 8192;
            const int colL2 = nt2 * 16 + l15;
            const int col_c = 32 * g + colL2;
            #pragma unroll
            for (int r = 0; r < 4; ++r) {
                int row = mt2 * 16 + l4 * 4 + r;
                float sv = acc2[r] + b2f(XCs[row * 32 + colL2]);
                float cv = tanhf(sv);
                float uu = USH[row][colL2];
                float ho = HOWN[row][colL2];
                bool act = (t < Ls[row]);
                float hn = act ? (uu * ho + (1.f - uu) * cv) : ho;
                unsigned short hnb = f2b(hn);
                out[((size_t)row * TC + tt) * 512 + col_c] = act ? hnb : (unsigned short)0;
                unsigned int ph = hnb;
                unsigned int po = (unsigned int)__shfl_xor((int)ph, 1);
                if (!(lane & 1))
                    __hip_atomic_store(hbs + row * 256 + 16 * g + (colL2 >> 1),
                                       ph | (po << 16),
                                       __ATOMIC_RELAXED, __HIP_MEMORY_SCOPE_AGENT);
                HOWN[row][colL2] = hn;
            }
        } else if (i + 1 < TC) {
            int ttn = dir ? (tt - 1) : (tt + 1);
            int jd = tid - 256;
            int b = jd >> 3, part = jd & 7;
            int srcc = (part < 4) ? (32 * g + part * 8) : (512 + 32 * g + (part - 4) * 8);
            *(us8*)(XGs + b * 64 + part * 8) =
                *(const us8*)(X + ((size_t)b * TC + ttn) * 1536 + srcc);
        }
        __syncthreads();                           // drains h stores
        if (tid == 0)
            __hip_atomic_store(myfH, s + 1, __ATOMIC_RELAXED, __HIP_MEMORY_SCOPE_AGENT);
    }

    // persist own f32 h slice for next chunk
    for (int j = tid; j < 1024; j += 512) {
        int row = j >> 5, lc = j & 31;
        hf32[row * 512 + 32 * g + lc] = HOWN[row][lc];
    }
}

// ---------------- launcher ----------------

extern "C" void kernel_launch(void* const* d_in, const int* in_sizes, int n_in,
                              void* d_out, int out_size, void* d_ws, size_t ws_size,
                              hipStream_t stream) {
    (void)in_sizes; (void)n_in; (void)out_size; (void)ws_size;
    const float* x    = (const float*)d_in[0];
    const int*   seq  = (const int*)  d_in[1];
    const float* w1   = (const float*)d_in[2];
    const float* b1   = (const float*)d_in[3];
    const float* w2   = (const float*)d_in[4];
    const float* b2   = (const float*)d_in[5];
    const float* wg_f = (const float*)d_in[6];
    const float* bg_f = (const float*)d_in[7];
    const float* wc_f = (const float*)d_in[8];
    const float* bc_f = (const float*)d_in[9];
    const float* wg_b = (const float*)d_in[10];
    const float* bg_b = (const float*)d_in[11];
    const float* wc_b = (const float*)d_in[12];
    const float* bc_b = (const float*)d_in[13];
    const float* wf   = (const float*)d_in[14];
    const float* bfv  = (const float*)d_in[15];

    char* p = (char*)d_ws;
    auto alloc = [&](size_t bytes) { char* q = p; p += (bytes + 255) & ~(size_t)255; return q; };

    // persistent weight buffers
    unsigned short* w1T     = (unsigned short*)alloc(512 * 192 * 2);
    unsigned short* w2T     = (unsigned short*)alloc(512 * 512 * 2);
    unsigned short* wx_f    = (unsigned short*)alloc((size_t)1536 * 512 * 2);   // x-half (k0=0)
    unsigned short* wx_b    = (unsigned short*)alloc((size_t)1536 * 512 * 2);
    unsigned short* wh_f    = (unsigned short*)alloc((size_t)1536 * 512 * 2);   // h-half (k0=512)
    unsigned short* wh_b    = (unsigned short*)alloc((size_t)1536 * 512 * 2);
    unsigned short* wfT_top = (unsigned short*)alloc(64 * 512 * 2);
    unsigned short* wfT_bot = (unsigned short*)alloc(64 * 512 * 2);
    float*          bcat    = (float*)         alloc(2 * 1536 * 4);

    // hB persistent through chunk phase (32.8 MB)
    unsigned short* hB = (unsigned short*)alloc((size_t)BT_ * 512 * 2);

    // union region: {xb, h1} (front-end) aliases {Xf, Xb, of, ob} (chunk phase)
    char* U = alloc((size_t)MCH * 1536 * 2 * 2 + (size_t)MCH * 512 * 2 * 2);
    unsigned short* xb = (unsigned short*)U;
    unsigned short* h1 = (unsigned short*)(U + (size_t)BT_ * 192 * 2);
    unsigned short* Xf = (unsigned short*)U;
    unsigned short* Xb = (unsigned short*)(U + (size_t)MCH * 1536 * 2);
    unsigned short* of = (unsigned short*)(U + (size_t)MCH * 1536 * 2 * 2);
    unsigned short* ob = (unsigned short*)(U + (size_t)MCH * 1536 * 2 * 2 + (size_t)MCH * 512 * 2);

    // GRU state/comm (outside union). fH|fR|claim contiguous for one memset.
    unsigned int*   fH_gl    = (unsigned int*)alloc(2 * 256 * 4);   // 2048 B
    unsigned int*   fR_gl    = (unsigned int*)alloc(2 * 256 * 4);   // 2048 B
    int*            claim    = (int*)         alloc(256);
    float*          hf32_gl  = (float*)       alloc((size_t)2 * 32 * 512 * 4);
    unsigned int*   hb_gl    = (unsigned int*)alloc((size_t)2 * 2 * 8192 * 4);  // 2 slots
    unsigned int*   rh_gl    = (unsigned int*)alloc((size_t)2 * 2 * 8192 * 4);

    hipMemsetAsync(d_out, 0, (size_t)BT_ * C_ * 4, stream);
    hipMemsetAsync(fH_gl, 0, 2 * 256 * 4 + 2 * 256 * 4 + 256, stream);

    // ---- weight prep ----
    transpose_cvt<<<(512 * 192) / 256, 256, 0, stream>>>(w1, w1T, 161, 512, 0, 192, 512);
    transpose_cvt<<<(512 * 512) / 256, 256, 0, stream>>>(w2, w2T, 512, 512, 0, 512, 512);
    transpose_cvt<<<(1024 * 512) / 256, 256, 0, stream>>>(wg_f, wx_f, 512, 1024, 0, 512, 1024);
    transpose_cvt<<<(512 * 512) / 256, 256, 0, stream>>>(wc_f, wx_f + (size_t)1024 * 512, 512, 512, 0, 512, 512);
    transpose_cvt<<<(1024 * 512) / 256, 256, 0, stream>>>(wg_b, wx_b, 512, 1024, 0, 512, 1024);
    transpose_cvt<<<(512 * 512) / 256, 256, 0, stream>>>(wc_b, wx_b + (size_t)1024 * 512, 512, 512, 0, 512, 512);
    transpose_cvt<<<(1024 * 512) / 256, 256, 0, stream>>>(wg_f, wh_f, 512, 1024, 512, 512, 1024);
    transpose_cvt<<<(512 * 512) / 256, 256, 0, stream>>>(wc_f, wh_f + (size_t)1024 * 512, 512, 512, 512, 512, 512);
    transpose_cvt<<<(1024 * 512) / 256, 256, 0, stream>>>(wg_b, wh_b, 512, 1024, 512, 512, 1024);
    transpose_cvt<<<(512 * 512) / 256, 256, 0, stream>>>(wc_b, wh_b + (size_t)1024 * 512, 512, 512, 512, 512, 512);
    transpose_cvt<<<(64 * 512) / 256, 256, 0, stream>>>(wf, wfT_top, 512, 62, 0, 512, 64);
    transpose_cvt<<<(64 * 512) / 256, 256, 0, stream>>>(wf, wfT_bot, 512, 62, 512, 512, 64);
    biascat<<<(2 * 1536 + 255) / 256, 256, 0, stream>>>(bg_f, bc_f, bg_b, bc_b, bcat);

    // ---- dense front-end ----
    cvt_x_pad<<<(BT_ * 192 + 255) / 256, 256, 0, stream>>>(x, xb);
    gemm_bf16<true, 0, false><<<dim3(BT_ / BM, 512 / BN), 256, 0, stream>>>(xb, w1T, b1, h1, 192, 512, 0);
    gemm_bf16<true, 0, false><<<dim3(BT_ / BM, 512 / BN), 256, 0, stream>>>(h1, w2T, b2, hB, 512, 512, 0);

    // ---- chunked BiGRU + projection ----
    for (int c = 0; c < NCH; ++c) {
        const int t0f = c * TC;
        const int t0b = (NCH - 1 - c) * TC;
        gemm_bf16<false, 0, true><<<dim3(MCH / BM, 1536 / BN), 256, 0, stream>>>(hB, wx_f, bcat,        Xf, 512, 1536, t0f);
        gemm_bf16<false, 0, true><<<dim3(MCH / BM, 1536 / BN), 256, 0, stream>>>(hB, wx_b, bcat + 1536, Xb, 512, 1536, t0b);
        gru_persist<<<256, 512, 0, stream>>>(wh_f, wh_b, Xf, Xb, seq, hf32_gl,
                                             hb_gl, rh_gl, fH_gl, fR_gl, claim + 2 * c,
                                             of, ob, t0f, t0b, c * TC, c == 0 ? 1 : 0);
        gemm_bf16<false, 1, false><<<dim3(MCH / BM, 1), 256, 0, stream>>>(of, wfT_top, bfv,     d_out, 512, C_, t0f);
        gemm_bf16<false, 1, false><<<dim3(MCH / BM, 1), 256, 0, stream>>>(ob, wfT_bot, nullptr, d_out, 512, C_, t0b);
    }
}